// Round 10
// baseline (154.169 us; speedup 1.0000x reference)
//
#include <hip/hip_runtime.h>
#include <hip/hip_bf16.h>
#include <stdint.h>

// B=32, C=128->128, 56x56, 3x3 pad 1, two quantized branches fused as one
// conv with IC2=256.  R15: same 128m x 128oc block as R14 (LDS 68 KB, 2
// blocks/CU) but 4 waves of 64m x 64oc instead of 8 of 64x32: LDS-read
// bytes/step drop (4+2)*8 -> (4+4)*4 fragment-KB (-33%) at identical MFMA
// work and identical effective TLP (8 waves/CU = R14's measured residency).
#define BATCH 32
#define CH 128
#define HH 56
#define WW 56
#define HW 3136
#define M_TOTAL (BATCH*HW)
#define PLANE ((size_t)M_TOTAL * 16)   // bytes per 16B-chunk plane

using int4v   = __attribute__((ext_vector_type(4))) int;
using float4v = __attribute__((ext_vector_type(4))) float;

// ws layout (bytes):
//   wqb : i8  [9][128 oc][256 ic2] = 294,912  (B^T: ic contiguous)
//   scb : f32 sc_h[128], sc_l[128], bias[128] = 1,536
//   zp  : 256 B pattern page (bytes 0..127 = 0x80, 128..255 = 0x00)
//   aqn : i8  [16 planes][M_TOTAL pos][16 B] = 25,690,112
//         plane = branch*8 + cg  (high: planes 0-7, zp 0x80; low: 8-15, zp 0)
#define WQB_OFF 0
#define SCB_OFF 294912
#define ZP_OFF  296448
#define AQN_OFF 296704

#define GLD_LDS16(g, l)                                                        \
  __builtin_amdgcn_global_load_lds(                                            \
      (const __attribute__((address_space(1))) void*)(g),                      \
      (__attribute__((address_space(3))) void*)(l), 16, 0, 0)

#define KSTR 484   // per-channel LDS stride (floats): 8*60 + 4 pad

// ---------------- Kernel 1: fused prep (mask+act quant | weight quant) ------
// Blocks 0..1791: maskquant (b, 8-row band, 16-ch group).
// Blocks 1792..2047: per-OC weight quant -> int8 B^T + scales.
__global__ __launch_bounds__(256) void prep_kernel(
    const float* __restrict__ x,
    const float* __restrict__ wh, const float* __restrict__ wl,
    const float* __restrict__ p_sh, const float* __restrict__ p_sl,
    char* __restrict__ wqb, float* __restrict__ scb, int* __restrict__ zp,
    char* __restrict__ aqn) {
  __shared__ __align__(16) float smem[16 * KSTR + 128];  // 31.4 KB
  int t = threadIdx.x;

  if (blockIdx.x >= BATCH * 7 * 8) {
    // ---------------- weight-quant path ----------------
    int blk = blockIdx.x - BATCH * 7 * 8;
    int which = blk >> 7, oc = blk & 127;
    if (blk == 0 && t < 64)
      zp[t] = (t < 32) ? 0x80808080 : 0;  // pad pattern page
    const float* src = (which ? wl : wh) + (size_t)oc * 1152;
    float n = which ? 7.0f : 127.0f;  // signed narrow-range 2^(b-1)-1
    float* red = smem;
    int* ired = (int*)(smem + 256);

    float m = 0.0f;
    for (int e = t; e < 1152; e += 256) m = fmaxf(m, fabsf(src[e]));
    red[t] = m;
    __syncthreads();
    for (int s = 128; s > 0; s >>= 1) {
      if (t < s) red[t] = fmaxf(red[t], red[t + s]);
      __syncthreads();
    }
    float scale = red[0] / n;

    int partial = 0;
    for (int e = t; e < 1152; e += 256) {
      int tt = e >> 7, ic = e & 127;
      float q = rintf(src[ic * 9 + tt] / scale);  // jnp.round = RNE
      q = fminf(fmaxf(q, -n), n);
      int k = (int)q;
      partial += k;
      wqb[((size_t)tt * 128 + oc) * 256 + which * 128 + ic] = (char)k;
    }
    ired[t] = partial;
    __syncthreads();
    for (int s = 128; s > 0; s >>= 1) {
      if (t < s) ired[t] += ired[t + s];
      __syncthreads();
    }
    if (t == 0) {
      float s_act = which ? p_sl[0] : p_sh[0];
      float sc = s_act * scale;
      if (which == 0) {
        scb[oc] = sc;                                   // sc_h
        scb[256 + oc] = sc * 128.0f * (float)ired[0];   // offset-corr bias
      } else {
        scb[128 + oc] = sc;                             // sc_l
      }
    }
    return;
  }

  // ---------------- mask + act-quant path ----------------
  int bi = blockIdx.x;            // (b*7 + band)*8 + cg
  int cg = bi & 7;
  int bb = bi >> 3;
  int b = bb / 7, band = bb - b * 7;
  float* sx = smem;                       // [16][KSTR]
  float* smk = smem + 16 * KSTR;          // [16][7]
  #pragma unroll
  for (int i = 0; i < 7; ++i) {           // 1792 float4 = 16 k x 8 r x 14
    int idx = i * 256 + t;
    int k = idx / 112, rem = idx - k * 112;
    int r = rem / 14, w4 = rem - r * 14;
    *(float4v*)(sx + k * KSTR + r * 60 + w4 * 4) =
        *(const float4v*)(x + ((size_t)(b * 128 + cg * 16 + k)) * HW
                            + (band * 8 + r) * 56 + w4 * 4);
  }
  __syncthreads();
  if (t < 112) {                          // 16 k x 7 cells
    int k = t / 7, bw = t - (t / 7) * 7;
    float s = 0.0f;
    #pragma unroll
    for (int r = 0; r < 8; ++r)
      #pragma unroll
      for (int j = 0; j < 8; ++j)
        s += sx[k * KSTR + r * 60 + bw * 8 + j];
    smk[t] = (s * (1.0f / 64.0f) >= 0.05f) ? 1.0f : 0.0f;
  }
  __syncthreads();
  float shs = p_sh[0], sls = p_sl[0];
  #pragma unroll
  for (int it = 0; it < 2; ++it) {
    int pos = it * 256 + t;               // 448 = 8 r x 56 w
    if (pos < 448) {
      int r = pos / 56, w = pos - r * 56;
      int h = band * 8 + r;
      size_t gp = (size_t)b * HW + (size_t)h * 56 + w;   // position index
      int hw_[4] = {0, 0, 0, 0}, lw_[4] = {0, 0, 0, 0};
      int mcell = w >> 3;
      #pragma unroll
      for (int k = 0; k < 16; ++k) {
        float xv = sx[k * KSTR + r * 60 + w];
        bool mk = smk[k * 7 + mcell] != 0.0f;
        float xh = mk ? xv : 1e-5f;
        int kh = (int)fminf(fmaxf(rintf(xh / shs), 0.0f), 255.0f) - 128;
        float xl = mk ? 1e-5f : xv;
        int kl = (int)fminf(fmaxf(rintf(xl / sls), 0.0f), 15.0f);
        hw_[k >> 2] |= (kh & 0xff) << ((k & 3) * 8);
        lw_[k >> 2] |= (kl & 0xff) << ((k & 3) * 8);
      }
      *(int4v*)(aqn + ((size_t)cg * M_TOTAL + gp) * 16) =
          (int4v){hw_[0], hw_[1], hw_[2], hw_[3]};                 // high
      *(int4v*)(aqn + ((size_t)(8 + cg) * M_TOTAL + gp) * 16) =
          (int4v){lw_[0], lw_[1], lw_[2], lw_[3]};                 // low
    }
  }
}

// ---------------- Kernel 2: implicit-GEMM i8 MFMA conv ----------------------
// Grid: 784 m-tiles (XCD-chunked), one block per tile.  Block 128m x 128oc,
// 4 waves (2 wm x 2 wn) of 64m x 64oc.  A 2x10KB, B 2x24KB double-buffered;
// 1-deep GLD_LDS prefetch; __syncthreads per step.  68 KB -> 2 blocks/CU.
__global__ __launch_bounds__(256, 2) void conv_mfma_kernel(
    const char* __restrict__ wqb,
    const char* __restrict__ aqn,
    const char* __restrict__ zp,
    const float* __restrict__ scb,
    float* __restrict__ out) {
  __shared__ __align__(16) char As[2][160 * 64];  // 2 x 10 KB (16-row halo)
  __shared__ __align__(16) char Bs[2][384 * 64];  // 2 x 24 KB (3 taps x 128 oc)

  int tid = threadIdx.x;
  int lane = tid & 63, wv = tid >> 6;              // 4 waves
  int wm = wv >> 1, wn = wv & 1;                   // 2 m-halves x 2 oc-halves
  int lr = lane & 15, quad = lane >> 4;
  int bx = blockIdx.x;
  int m0 = (((bx & 7) * 98) + (bx >> 3)) * 128;   // bijective XCD chunking

  // ---- A staging: 10 groups of 16 rows; wave w -> {w, w+4, w+8(w<2)}
  int ng = (wv < 2) ? 3 : 2;
  int sgrp[3] = {wv, wv + 4, wv + 8};
  const char* abase[3];
  const char* zbase[3];
  int avalid[3], ah[3];
  #pragma unroll
  for (int j = 0; j < 3; ++j) {
    int slot = sgrp[j] * 16 + (lane >> 2);
    int q = ((lane & 3) ^ (slot >> 1)) & 3;     // XOR-swizzled quarter/plane
    int p = m0 + slot - 16;                     // rows m0-16 .. m0+143
    int pv = (p >= 0) && (p < M_TOTAL);
    int pc = pv ? p : 0;
    int bb = pc / HW, rem = pc - bb * HW;
    int hh = rem / 56;
    abase[j] = aqn + (size_t)q * PLANE + (size_t)pc * 16;
    zbase[j] = zp + q * 16;
    avalid[j] = pv;
    ah[j] = hh;
  }
  // ---- B staging: 24 groups of 16 rows (384 rows = [dwi 3][ocr 128]);
  //      wave w takes groups w*6 .. w*6+5.
  const char* bbase[6];
  #pragma unroll
  for (int i = 0; i < 6; ++i) {
    int slot = (wv * 6 + i) * 16 + (lane >> 2);      // 0..383
    int qp = (((lane & 3) ^ (slot >> 1)) & 3) * 16;
    int dwi_s = slot >> 7, ocr = slot & 127;
    bbase[i] = wqb + ((size_t)(dwi_s * 128 + ocr)) * 256 + qp;
  }
  // ---- w-edge masks per m-fragment
  int lo_ok[4], hi_ok[4];
  #pragma unroll
  for (int mi = 0; mi < 4; ++mi) {
    int m = m0 + wm * 64 + mi * 16 + lr;
    int w = (m % HW) % 56;
    lo_ok[mi] = (w > 0);
    hi_ok[mi] = (w < 55);
  }

  int4v acch[4][4], accl[4][4];
  #pragma unroll
  for (int mi = 0; mi < 4; ++mi)
    #pragma unroll
    for (int ni = 0; ni < 4; ++ni) {
      acch[mi][ni] = (int4v){0, 0, 0, 0};
      accl[mi][ni] = (int4v){0, 0, 0, 0};
    }

  // stage A for step s (s = dh3*4 + icc) into buffer A
  auto stageA = [&](int s, char* A) {
    int dh3 = s >> 2, icc = s & 3;
    int dh = dh3 - 1;
    #pragma unroll
    for (int j = 0; j < 3; ++j) {
      if (j < ng) {
        int h2 = ah[j] + dh;
        bool ok = avalid[j] && ((unsigned)h2 < (unsigned)HH);
        const char* p = ok ? (abase[j] + dh * (56 * 16) + (size_t)icc * (4 * PLANE))
                           : (zbase[j] + icc * 64);
        GLD_LDS16(p, A + sgrp[j] * 1024);
      }
    }
  };
  // stage B for step s into buffer B (6 groups per wave)
  auto stageB = [&](int s, char* B) {
    int dh3 = s >> 2, icc = s & 3;
    #pragma unroll
    for (int i = 0; i < 6; ++i)
      GLD_LDS16(bbase[i] + (size_t)dh3 * 98304 + icc * 64,
                B + ((wv * 6 + i) * 16) * 64);
  };

  // compute step s from buffers A,B: per dwi, 4 af + 4 bf reads -> 16 MFMA
  auto compute = [&](int s, const char* A, const char* B) {
    int icc = s & 3;
    const bool high = (icc < 2);
    const int patv = high ? (int)0x80808080 : 0;  // pad byte per branch
    const int4v pat = (int4v){patv, patv, patv, patv};
    #pragma unroll
    for (int dwi = 0; dwi < 3; ++dwi) {
      int4v af[4], bf[4];
      #pragma unroll
      for (int mi = 0; mi < 4; ++mi) {
        int sA = wm * 64 + mi * 16 + lr + 15 + dwi;
        af[mi] = *(const int4v*)(A + sA * 64 + (((quad ^ (sA >> 1)) & 3) * 16));
        bool ok = (dwi == 1) | (dwi == 0 ? lo_ok[mi] : hi_ok[mi]);
        af[mi] = ok ? af[mi] : pat;
      }
      #pragma unroll
      for (int ni = 0; ni < 4; ++ni) {
        int sB = dwi * 128 + wn * 64 + ni * 16 + lr;
        bf[ni] = *(const int4v*)(B + sB * 64 + (((quad ^ (sB >> 1)) & 3) * 16));
      }
      __builtin_amdgcn_s_setprio(1);
      if (high) {
        #pragma unroll
        for (int mi = 0; mi < 4; ++mi)
          #pragma unroll
          for (int ni = 0; ni < 4; ++ni)
            acch[mi][ni] = __builtin_amdgcn_mfma_i32_16x16x64_i8(
                af[mi], bf[ni], acch[mi][ni], 0, 0, 0);
      } else {
        #pragma unroll
        for (int mi = 0; mi < 4; ++mi)
          #pragma unroll
          for (int ni = 0; ni < 4; ++ni)
            accl[mi][ni] = __builtin_amdgcn_mfma_i32_16x16x64_i8(
                af[mi], bf[ni], accl[mi][ni], 0, 0, 0);
      }
      __builtin_amdgcn_s_setprio(0);
    }
  };

  // ---- pipeline (R7-proven skeleton): prefetch s+1, compute s, one
  // __syncthreads per step.
  stageA(0, As[0]);
  stageB(0, Bs[0]);
  __syncthreads();
  #pragma unroll
  for (int s = 0; s < 12; ++s) {
    if (s < 11) {
      stageB(s + 1, Bs[(s + 1) & 1]);
      stageA(s + 1, As[(s + 1) & 1]);
    }
    compute(s, As[s & 1], Bs[s & 1]);
    __syncthreads();
  }

  // ---- Epilogue: y = sc_h*acc_h + sc_l*acc_l + bias, plain dwordx4 stores
  #pragma unroll
  for (int mi = 0; mi < 4; ++mi) {
    int m = m0 + wm * 64 + mi * 16 + quad * 4;
    int b = m / HW, r = m - b * HW;
    float* obase = out + (size_t)b * (CH * HW) + r;
    #pragma unroll
    for (int ni = 0; ni < 4; ++ni) {
      int oc = wn * 64 + ni * 16 + lr;
      float sch = scb[oc], scl = scb[128 + oc], bs = scb[256 + oc];
      float4v f;
      #pragma unroll
      for (int rg = 0; rg < 4; ++rg)
        f[rg] = sch * (float)acch[mi][ni][rg] + scl * (float)accl[mi][ni][rg] + bs;
      *(float4v*)(obase + (size_t)oc * HW) = f;
    }
  }
}

extern "C" void kernel_launch(void* const* d_in, const int* in_sizes, int n_in,
                              void* d_out, int out_size, void* d_ws, size_t ws_size,
                              hipStream_t stream) {
  const float* x  = (const float*)d_in[0];
  const float* wh = (const float*)d_in[1];
  const float* wl = (const float*)d_in[2];
  const float* sh = (const float*)d_in[3];
  const float* sl = (const float*)d_in[4];
  float* out = (float*)d_out;

  char* ws = (char*)d_ws;
  char* wqb  = ws + WQB_OFF;
  float* scb = (float*)(ws + SCB_OFF);
  int* zp    = (int*)(ws + ZP_OFF);
  char* aqn  = ws + AQN_OFF;

  prep_kernel<<<dim3(BATCH * 7 * 8 + 256), dim3(256), 0, stream>>>(
      x, wh, wl, sh, sl, wqb, scb, zp, aqn);
  conv_mfma_kernel<<<dim3(M_TOTAL / 128), dim3(256), 0, stream>>>(
      wqb, aqn, (const char*)zp, scb, out);
}

// Round 11
// 151.783 us; speedup vs baseline: 1.0157x; 1.0157x over previous
//
#include <hip/hip_runtime.h>
#include <hip/hip_bf16.h>
#include <stdint.h>

// B=32, C=128->128, 56x56, 3x3 pad 1, two quantized branches fused as one
// conv with IC2=256.  R16: R14 conv (best: 128x128 block, 8 waves of
// 64m x 32oc, 50.2us) + XCD-local producer/consumer remap: maskquant blocks
// are dispatched so each band (b,band) is written on the SAME XCD whose conv
// blocks consume it (band J in [28k,28k+28) -> XCD k; exact 224=8*28 split).
// Kills the 14/16 cross-XCD L2 misses on conv's A staging.
#define BATCH 32
#define CH 128
#define HH 56
#define WW 56
#define HW 3136
#define M_TOTAL (BATCH*HW)
#define PLANE ((size_t)M_TOTAL * 16)   // bytes per 16B-chunk plane

using int4v   = __attribute__((ext_vector_type(4))) int;
using float4v = __attribute__((ext_vector_type(4))) float;

// ws layout (bytes):
//   wqb : i8  [9][128 oc][256 ic2] = 294,912  (B^T: ic contiguous)
//   scb : f32 sc_h[128], sc_l[128], bias[128] = 1,536
//   zp  : 256 B pattern page (bytes 0..127 = 0x80, 128..255 = 0x00)
//   aqn : i8  [16 planes][M_TOTAL pos][16 B] = 25,690,112
//         plane = branch*8 + cg  (high: planes 0-7, zp 0x80; low: 8-15, zp 0)
#define WQB_OFF 0
#define SCB_OFF 294912
#define ZP_OFF  296448
#define AQN_OFF 296704

#define GLD_LDS16(g, l)                                                        \
  __builtin_amdgcn_global_load_lds(                                            \
      (const __attribute__((address_space(1))) void*)(g),                      \
      (__attribute__((address_space(3))) void*)(l), 16, 0, 0)

#define KSTR 484   // per-channel LDS stride (floats): 8*60 + 4 pad

// ---------------- Kernel 1: fused prep (mask+act quant | weight quant) ------
// Blocks 0..1791: maskquant, XCD-matched to the conv consumer:
//   bi = xcd + 8*(cg + 8*Jlocal), J = xcd*28 + Jlocal = b*7+band.
// Blocks 1792..2047: per-OC weight quant -> int8 B^T + scales.
__global__ __launch_bounds__(256) void prep_kernel(
    const float* __restrict__ x,
    const float* __restrict__ wh, const float* __restrict__ wl,
    const float* __restrict__ p_sh, const float* __restrict__ p_sl,
    char* __restrict__ wqb, float* __restrict__ scb, int* __restrict__ zp,
    char* __restrict__ aqn) {
  __shared__ __align__(16) float smem[16 * KSTR + 128];  // 31.4 KB
  int t = threadIdx.x;

  if (blockIdx.x >= BATCH * 7 * 8) {
    // ---------------- weight-quant path ----------------
    int blk = blockIdx.x - BATCH * 7 * 8;
    int which = blk >> 7, oc = blk & 127;
    if (blk == 0 && t < 64)
      zp[t] = (t < 32) ? 0x80808080 : 0;  // pad pattern page
    const float* src = (which ? wl : wh) + (size_t)oc * 1152;
    float n = which ? 7.0f : 127.0f;  // signed narrow-range 2^(b-1)-1
    float* red = smem;
    int* ired = (int*)(smem + 256);

    float m = 0.0f;
    for (int e = t; e < 1152; e += 256) m = fmaxf(m, fabsf(src[e]));
    red[t] = m;
    __syncthreads();
    for (int s = 128; s > 0; s >>= 1) {
      if (t < s) red[t] = fmaxf(red[t], red[t + s]);
      __syncthreads();
    }
    float scale = red[0] / n;

    int partial = 0;
    for (int e = t; e < 1152; e += 256) {
      int tt = e >> 7, ic = e & 127;
      float q = rintf(src[ic * 9 + tt] / scale);  // jnp.round = RNE
      q = fminf(fmaxf(q, -n), n);
      int k = (int)q;
      partial += k;
      wqb[((size_t)tt * 128 + oc) * 256 + which * 128 + ic] = (char)k;
    }
    ired[t] = partial;
    __syncthreads();
    for (int s = 128; s > 0; s >>= 1) {
      if (t < s) ired[t] += ired[t + s];
      __syncthreads();
    }
    if (t == 0) {
      float s_act = which ? p_sl[0] : p_sh[0];
      float sc = s_act * scale;
      if (which == 0) {
        scb[oc] = sc;                                   // sc_h
        scb[256 + oc] = sc * 128.0f * (float)ired[0];   // offset-corr bias
      } else {
        scb[128 + oc] = sc;                             // sc_l
      }
    }
    return;
  }

  // ---------------- mask + act-quant path ----------------
  // XCD-matched decode: conv XCD k consumes bands J in [28k, 28(k+1)).
  int bi = blockIdx.x;
  int xcd = bi & 7;
  int r = bi >> 3;
  int cg = r & 7;
  int J = xcd * 28 + (r >> 3);          // J = b*7 + band, [0,224)
  int b = J / 7, band = J - b * 7;
  float* sx = smem;                       // [16][KSTR]
  float* smk = smem + 16 * KSTR;          // [16][7]
  #pragma unroll
  for (int i = 0; i < 7; ++i) {           // 1792 float4 = 16 k x 8 r x 14
    int idx = i * 256 + t;
    int k = idx / 112, rem = idx - k * 112;
    int rr = rem / 14, w4 = rem - rr * 14;
    *(float4v*)(sx + k * KSTR + rr * 60 + w4 * 4) =
        *(const float4v*)(x + ((size_t)(b * 128 + cg * 16 + k)) * HW
                            + (band * 8 + rr) * 56 + w4 * 4);
  }
  __syncthreads();
  if (t < 112) {                          // 16 k x 7 cells
    int k = t / 7, bw = t - (t / 7) * 7;
    float s = 0.0f;
    #pragma unroll
    for (int rr = 0; rr < 8; ++rr)
      #pragma unroll
      for (int j = 0; j < 8; ++j)
        s += sx[k * KSTR + rr * 60 + bw * 8 + j];
    smk[t] = (s * (1.0f / 64.0f) >= 0.05f) ? 1.0f : 0.0f;
  }
  __syncthreads();
  float shs = p_sh[0], sls = p_sl[0];
  #pragma unroll
  for (int it = 0; it < 2; ++it) {
    int pos = it * 256 + t;               // 448 = 8 r x 56 w
    if (pos < 448) {
      int rr = pos / 56, w = pos - rr * 56;
      int h = band * 8 + rr;
      size_t gp = (size_t)b * HW + (size_t)h * 56 + w;   // position index
      int hw_[4] = {0, 0, 0, 0}, lw_[4] = {0, 0, 0, 0};
      int mcell = w >> 3;
      #pragma unroll
      for (int k = 0; k < 16; ++k) {
        float xv = sx[k * KSTR + rr * 60 + w];
        bool mk = smk[k * 7 + mcell] != 0.0f;
        float xh = mk ? xv : 1e-5f;
        int kh = (int)fminf(fmaxf(rintf(xh / shs), 0.0f), 255.0f) - 128;
        float xl = mk ? 1e-5f : xv;
        int kl = (int)fminf(fmaxf(rintf(xl / sls), 0.0f), 15.0f);
        hw_[k >> 2] |= (kh & 0xff) << ((k & 3) * 8);
        lw_[k >> 2] |= (kl & 0xff) << ((k & 3) * 8);
      }
      *(int4v*)(aqn + ((size_t)cg * M_TOTAL + gp) * 16) =
          (int4v){hw_[0], hw_[1], hw_[2], hw_[3]};                 // high
      *(int4v*)(aqn + ((size_t)(8 + cg) * M_TOTAL + gp) * 16) =
          (int4v){lw_[0], lw_[1], lw_[2], lw_[3]};                 // low
    }
  }
}

// ---------------- Kernel 2: implicit-GEMM i8 MFMA conv ----------------------
// Grid: 784 m-tiles (XCD-chunked), one block per tile.  Block 128m x 128oc,
// 8 waves (2 wm x 4 wn) of 64m x 32oc each (R2-proven wave tile).  A 2x10KB,
// B 2x24KB (3 taps x 128 oc) double-buffered; 1-deep GLD_LDS prefetch;
// __syncthreads per step.  68 KB LDS -> 2 blocks/CU = 16 waves/CU.
__global__ __launch_bounds__(512, 4) void conv_mfma_kernel(
    const char* __restrict__ wqb,
    const char* __restrict__ aqn,
    const char* __restrict__ zp,
    const float* __restrict__ scb,
    float* __restrict__ out) {
  __shared__ __align__(16) char As[2][160 * 64];  // 2 x 10 KB (16-row halo)
  __shared__ __align__(16) char Bs[2][384 * 64];  // 2 x 24 KB (3 taps x 128 oc)

  int tid = threadIdx.x;
  int lane = tid & 63, wv = tid >> 6;              // 8 waves
  int wm = wv >> 2, wn = wv & 3;                   // 2 m-halves x 4 oc-quarters
  int lr = lane & 15, quad = lane >> 4;
  int bx = blockIdx.x;
  int m0 = (((bx & 7) * 98) + (bx >> 3)) * 128;   // bijective XCD chunking

  // ---- A staging: 10 groups of 16 rows; waves 0-7 take groups 0-7,
  //      waves 0,1 also take groups 8,9.
  int ng = (wv < 2) ? 2 : 1;
  int sgrp[2] = {wv, wv + 8};
  const char* abase[2];
  const char* zbase[2];
  int avalid[2], ah[2];
  #pragma unroll
  for (int j = 0; j < 2; ++j) {
    int slot = sgrp[j] * 16 + (lane >> 2);
    int q = ((lane & 3) ^ (slot >> 1)) & 3;     // XOR-swizzled quarter/plane
    int p = m0 + slot - 16;                     // rows m0-16 .. m0+143
    int pv = (p >= 0) && (p < M_TOTAL);
    int pc = pv ? p : 0;
    int bb = pc / HW, rem = pc - bb * HW;
    int hh = rem / 56;
    abase[j] = aqn + (size_t)q * PLANE + (size_t)pc * 16;
    zbase[j] = zp + q * 16;
    avalid[j] = pv;
    ah[j] = hh;
  }
  // ---- B staging: 24 groups of 16 rows (384 rows = [dwi 3][ocr 128]);
  //      wave w takes groups w*3 .. w*3+2.
  const char* bbase[3];
  #pragma unroll
  for (int i = 0; i < 3; ++i) {
    int slot = (wv * 3 + i) * 16 + (lane >> 2);      // 0..383
    int qp = (((lane & 3) ^ (slot >> 1)) & 3) * 16;
    int dwi_s = slot >> 7, ocr = slot & 127;
    bbase[i] = wqb + ((size_t)(dwi_s * 128 + ocr)) * 256 + qp;
  }
  // ---- w-edge masks per m-fragment
  int lo_ok[4], hi_ok[4];
  #pragma unroll
  for (int mi = 0; mi < 4; ++mi) {
    int m = m0 + wm * 64 + mi * 16 + lr;
    int w = (m % HW) % 56;
    lo_ok[mi] = (w > 0);
    hi_ok[mi] = (w < 55);
  }

  int4v acch[4][2], accl[4][2];
  #pragma unroll
  for (int mi = 0; mi < 4; ++mi)
    #pragma unroll
    for (int ni = 0; ni < 2; ++ni) {
      acch[mi][ni] = (int4v){0, 0, 0, 0};
      accl[mi][ni] = (int4v){0, 0, 0, 0};
    }

  // stage A for step s (s = dh3*4 + icc) into buffer A
  auto stageA = [&](int s, char* A) {
    int dh3 = s >> 2, icc = s & 3;
    int dh = dh3 - 1;
    #pragma unroll
    for (int j = 0; j < 2; ++j) {
      if (j < ng) {
        int h2 = ah[j] + dh;
        bool ok = avalid[j] && ((unsigned)h2 < (unsigned)HH);
        const char* p = ok ? (abase[j] + dh * (56 * 16) + (size_t)icc * (4 * PLANE))
                           : (zbase[j] + icc * 64);
        GLD_LDS16(p, A + sgrp[j] * 1024);
      }
    }
  };
  // stage B for step s into buffer B (3 groups per wave)
  auto stageB = [&](int s, char* B) {
    int dh3 = s >> 2, icc = s & 3;
    #pragma unroll
    for (int i = 0; i < 3; ++i)
      GLD_LDS16(bbase[i] + (size_t)dh3 * 98304 + icc * 64,
                B + ((wv * 3 + i) * 16) * 64);
  };

  // compute step s from buffers A,B
  auto compute = [&](int s, const char* A, const char* B) {
    int icc = s & 3;
    const bool high = (icc < 2);
    const int patv = high ? (int)0x80808080 : 0;  // pad byte per branch
    const int4v pat = (int4v){patv, patv, patv, patv};
    #pragma unroll
    for (int dwi = 0; dwi < 3; ++dwi) {
      int4v af[4], bf[2];
      #pragma unroll
      for (int mi = 0; mi < 4; ++mi) {
        int sA = wm * 64 + mi * 16 + lr + 15 + dwi;
        af[mi] = *(const int4v*)(A + sA * 64 + (((quad ^ (sA >> 1)) & 3) * 16));
        bool ok = (dwi == 1) | (dwi == 0 ? lo_ok[mi] : hi_ok[mi]);
        af[mi] = ok ? af[mi] : pat;
      }
      #pragma unroll
      for (int ni = 0; ni < 2; ++ni) {
        int sB = dwi * 128 + wn * 32 + ni * 16 + lr;
        bf[ni] = *(const int4v*)(B + sB * 64 + (((quad ^ (sB >> 1)) & 3) * 16));
      }
      __builtin_amdgcn_s_setprio(1);
      if (high) {
        #pragma unroll
        for (int mi = 0; mi < 4; ++mi)
          #pragma unroll
          for (int ni = 0; ni < 2; ++ni)
            acch[mi][ni] = __builtin_amdgcn_mfma_i32_16x16x64_i8(
                af[mi], bf[ni], acch[mi][ni], 0, 0, 0);
      } else {
        #pragma unroll
        for (int mi = 0; mi < 4; ++mi)
          #pragma unroll
          for (int ni = 0; ni < 2; ++ni)
            accl[mi][ni] = __builtin_amdgcn_mfma_i32_16x16x64_i8(
                af[mi], bf[ni], accl[mi][ni], 0, 0, 0);
      }
      __builtin_amdgcn_s_setprio(0);
    }
  };

  // ---- pipeline (R7-proven skeleton): prefetch s+1, compute s, one
  // __syncthreads per step.
  stageA(0, As[0]);
  stageB(0, Bs[0]);
  __syncthreads();
  #pragma unroll
  for (int s = 0; s < 12; ++s) {
    if (s < 11) {
      stageB(s + 1, Bs[(s + 1) & 1]);
      stageA(s + 1, As[(s + 1) & 1]);
    }
    compute(s, As[s & 1], Bs[s & 1]);
    __syncthreads();
  }

  // ---- Epilogue: y = sc_h*acc_h + sc_l*acc_l + bias, plain dwordx4 stores
  // (full 64B lines per wave: 4 quads x 4 consecutive m per lane-group).
  #pragma unroll
  for (int mi = 0; mi < 4; ++mi) {
    int m = m0 + wm * 64 + mi * 16 + quad * 4;
    int b = m / HW, r = m - b * HW;
    float* obase = out + (size_t)b * (CH * HW) + r;
    #pragma unroll
    for (int ni = 0; ni < 2; ++ni) {
      int oc = wn * 32 + ni * 16 + lr;
      float sch = scb[oc], scl = scb[128 + oc], bs = scb[256 + oc];
      float4v f;
      #pragma unroll
      for (int rg = 0; rg < 4; ++rg)
        f[rg] = sch * (float)acch[mi][ni][rg] + scl * (float)accl[mi][ni][rg] + bs;
      *(float4v*)(obase + (size_t)oc * HW) = f;
    }
  }
}

extern "C" void kernel_launch(void* const* d_in, const int* in_sizes, int n_in,
                              void* d_out, int out_size, void* d_ws, size_t ws_size,
                              hipStream_t stream) {
  const float* x  = (const float*)d_in[0];
  const float* wh = (const float*)d_in[1];
  const float* wl = (const float*)d_in[2];
  const float* sh = (const float*)d_in[3];
  const float* sl = (const float*)d_in[4];
  float* out = (float*)d_out;

  char* ws = (char*)d_ws;
  char* wqb  = ws + WQB_OFF;
  float* scb = (float*)(ws + SCB_OFF);
  int* zp    = (int*)(ws + ZP_OFF);
  char* aqn  = ws + AQN_OFF;

  prep_kernel<<<dim3(BATCH * 7 * 8 + 256), dim3(256), 0, stream>>>(
      x, wh, wl, sh, sl, wqb, scb, zp, aqn);
  conv_mfma_kernel<<<dim3(M_TOTAL / 128), dim3(512), 0, stream>>>(
      wqb, aqn, (const char*)zp, scb, out);
}

// Round 12
// 149.804 us; speedup vs baseline: 1.0291x; 1.0132x over previous
//
#include <hip/hip_runtime.h>
#include <hip/hip_bf16.h>
#include <stdint.h>

// B=32, C=128->128, 56x56, 3x3 pad 1, two quantized branches fused as one
// conv with IC2=256.  R17: R14 conv structure (best, 50.2us: 128m x 128oc
// block, 8 waves of 64m x 32oc, 2 blocks/CU) + R9's hardware-verified
// counted-vmcnt pipeline: A triple-buffered (2-deep prefetch), B double-
// buffered (1-deep), per-wave s_waitcnt vmcnt(nA) + one raw s_barrier per
// step -- next-step A loads ride across the barrier.  78 KB DYNAMIC LDS
// (static caps at 64KB); 2 x 78 = 156 <= 160 KB pool keeps 2 blocks/CU.
// Prep reverted to R14 dispatch (R16 remap was ~4% worse).
#define BATCH 32
#define CH 128
#define HH 56
#define WW 56
#define HW 3136
#define M_TOTAL (BATCH*HW)
#define PLANE ((size_t)M_TOTAL * 16)   // bytes per 16B-chunk plane

#define A_BUF 10240                    // 160 rows x 64 B
#define B_BUF 24576                    // 384 rows x 64 B
#define LDS_TOTAL (3*A_BUF + 2*B_BUF)  // 79,872 B

using int4v   = __attribute__((ext_vector_type(4))) int;
using float4v = __attribute__((ext_vector_type(4))) float;

// ws layout (bytes):
//   wqb : i8  [9][128 oc][256 ic2] = 294,912  (B^T: ic contiguous)
//   scb : f32 sc_h[128], sc_l[128], bias[128] = 1,536
//   zp  : 256 B pattern page (bytes 0..127 = 0x80, 128..255 = 0x00)
//   aqn : i8  [16 planes][M_TOTAL pos][16 B] = 25,690,112
//         plane = branch*8 + cg  (high: planes 0-7, zp 0x80; low: 8-15, zp 0)
#define WQB_OFF 0
#define SCB_OFF 294912
#define ZP_OFF  296448
#define AQN_OFF 296704

#define GLD_LDS16(g, l)                                                        \
  __builtin_amdgcn_global_load_lds(                                            \
      (const __attribute__((address_space(1))) void*)(g),                      \
      (__attribute__((address_space(3))) void*)(l), 16, 0, 0)

#define KSTR 484   // per-channel LDS stride (floats): 8*60 + 4 pad

// ---------------- Kernel 1: fused prep (mask+act quant | weight quant) ------
// Blocks 0..1791: maskquant (b, 8-row band, 16-ch group).
// Blocks 1792..2047: per-OC weight quant -> int8 B^T + scales.
__global__ __launch_bounds__(256) void prep_kernel(
    const float* __restrict__ x,
    const float* __restrict__ wh, const float* __restrict__ wl,
    const float* __restrict__ p_sh, const float* __restrict__ p_sl,
    char* __restrict__ wqb, float* __restrict__ scb, int* __restrict__ zp,
    char* __restrict__ aqn) {
  __shared__ __align__(16) float smem[16 * KSTR + 128];  // 31.4 KB
  int t = threadIdx.x;

  if (blockIdx.x >= BATCH * 7 * 8) {
    // ---------------- weight-quant path ----------------
    int blk = blockIdx.x - BATCH * 7 * 8;
    int which = blk >> 7, oc = blk & 127;
    if (blk == 0 && t < 64)
      zp[t] = (t < 32) ? 0x80808080 : 0;  // pad pattern page
    const float* src = (which ? wl : wh) + (size_t)oc * 1152;
    float n = which ? 7.0f : 127.0f;  // signed narrow-range 2^(b-1)-1
    float* red = smem;
    int* ired = (int*)(smem + 256);

    float m = 0.0f;
    for (int e = t; e < 1152; e += 256) m = fmaxf(m, fabsf(src[e]));
    red[t] = m;
    __syncthreads();
    for (int s = 128; s > 0; s >>= 1) {
      if (t < s) red[t] = fmaxf(red[t], red[t + s]);
      __syncthreads();
    }
    float scale = red[0] / n;

    int partial = 0;
    for (int e = t; e < 1152; e += 256) {
      int tt = e >> 7, ic = e & 127;
      float q = rintf(src[ic * 9 + tt] / scale);  // jnp.round = RNE
      q = fminf(fmaxf(q, -n), n);
      int k = (int)q;
      partial += k;
      wqb[((size_t)tt * 128 + oc) * 256 + which * 128 + ic] = (char)k;
    }
    ired[t] = partial;
    __syncthreads();
    for (int s = 128; s > 0; s >>= 1) {
      if (t < s) ired[t] += ired[t + s];
      __syncthreads();
    }
    if (t == 0) {
      float s_act = which ? p_sl[0] : p_sh[0];
      float sc = s_act * scale;
      if (which == 0) {
        scb[oc] = sc;                                   // sc_h
        scb[256 + oc] = sc * 128.0f * (float)ired[0];   // offset-corr bias
      } else {
        scb[128 + oc] = sc;                             // sc_l
      }
    }
    return;
  }

  // ---------------- mask + act-quant path ----------------
  int bi = blockIdx.x;            // (b*7 + band)*8 + cg
  int cg = bi & 7;
  int bb = bi >> 3;
  int b = bb / 7, band = bb - b * 7;
  float* sx = smem;                       // [16][KSTR]
  float* smk = smem + 16 * KSTR;          // [16][7]
  #pragma unroll
  for (int i = 0; i < 7; ++i) {           // 1792 float4 = 16 k x 8 r x 14
    int idx = i * 256 + t;
    int k = idx / 112, rem = idx - k * 112;
    int r = rem / 14, w4 = rem - r * 14;
    *(float4v*)(sx + k * KSTR + r * 60 + w4 * 4) =
        *(const float4v*)(x + ((size_t)(b * 128 + cg * 16 + k)) * HW
                            + (band * 8 + r) * 56 + w4 * 4);
  }
  __syncthreads();
  if (t < 112) {                          // 16 k x 7 cells
    int k = t / 7, bw = t - (t / 7) * 7;
    float s = 0.0f;
    #pragma unroll
    for (int r = 0; r < 8; ++r)
      #pragma unroll
      for (int j = 0; j < 8; ++j)
        s += sx[k * KSTR + r * 60 + bw * 8 + j];
    smk[t] = (s * (1.0f / 64.0f) >= 0.05f) ? 1.0f : 0.0f;
  }
  __syncthreads();
  float shs = p_sh[0], sls = p_sl[0];
  #pragma unroll
  for (int it = 0; it < 2; ++it) {
    int pos = it * 256 + t;               // 448 = 8 r x 56 w
    if (pos < 448) {
      int r = pos / 56, w = pos - r * 56;
      int h = band * 8 + r;
      size_t gp = (size_t)b * HW + (size_t)h * 56 + w;   // position index
      int hw_[4] = {0, 0, 0, 0}, lw_[4] = {0, 0, 0, 0};
      int mcell = w >> 3;
      #pragma unroll
      for (int k = 0; k < 16; ++k) {
        float xv = sx[k * KSTR + r * 60 + w];
        bool mk = smk[k * 7 + mcell] != 0.0f;
        float xh = mk ? xv : 1e-5f;
        int kh = (int)fminf(fmaxf(rintf(xh / shs), 0.0f), 255.0f) - 128;
        float xl = mk ? 1e-5f : xv;
        int kl = (int)fminf(fmaxf(rintf(xl / sls), 0.0f), 15.0f);
        hw_[k >> 2] |= (kh & 0xff) << ((k & 3) * 8);
        lw_[k >> 2] |= (kl & 0xff) << ((k & 3) * 8);
      }
      *(int4v*)(aqn + ((size_t)cg * M_TOTAL + gp) * 16) =
          (int4v){hw_[0], hw_[1], hw_[2], hw_[3]};                 // high
      *(int4v*)(aqn + ((size_t)(8 + cg) * M_TOTAL + gp) * 16) =
          (int4v){lw_[0], lw_[1], lw_[2], lw_[3]};                 // low
    }
  }
}

// ---------------- Kernel 2: implicit-GEMM i8 MFMA conv ----------------------
// Grid: 784 m-tiles (XCD-chunked), one block per tile.  Block 128m x 128oc,
// 8 waves (2 wm x 4 wn) of 64m x 32oc.  Dynamic LDS 78 KB: A 3-buf (2-deep
// prefetch), B 2-buf (1-deep).  Per-wave counted vmcnt(nA) + raw barrier per
// step; next-step A loads stay in flight across the barrier.  2 blocks/CU.
__global__ __launch_bounds__(512, 4) void conv_mfma_kernel(
    const char* __restrict__ wqb,
    const char* __restrict__ aqn,
    const char* __restrict__ zp,
    const float* __restrict__ scb,
    float* __restrict__ out) {
  extern __shared__ __align__(16) char lds[];
  char* As0 = lds;                 // 3 x A_BUF (160 rows x 64 B, 16-row halo)
  char* Bs0 = lds + 3 * A_BUF;     // 2 x B_BUF (384 rows = 3 taps x 128 oc)

  int tid = threadIdx.x;
  int lane = tid & 63, wv = tid >> 6;              // 8 waves
  int wm = wv >> 2, wn = wv & 3;                   // 2 m-halves x 4 oc-quarters
  int lr = lane & 15, quad = lane >> 4;
  int bx = blockIdx.x;
  int m0 = (((bx & 7) * 98) + (bx >> 3)) * 128;   // bijective XCD chunking

  // ---- A staging: 10 groups of 16 rows; waves 0-7 take groups 0-7,
  //      waves 0,1 also take groups 8,9.  nA = 2 (wv<2) else 1.
  int ng = (wv < 2) ? 2 : 1;
  int sgrp[2] = {wv, wv + 8};
  const char* abase[2];
  const char* zbase[2];
  int avalid[2], ah[2];
  #pragma unroll
  for (int j = 0; j < 2; ++j) {
    int slot = sgrp[j] * 16 + (lane >> 2);
    int q = ((lane & 3) ^ (slot >> 1)) & 3;     // XOR-swizzled quarter/plane
    int p = m0 + slot - 16;                     // rows m0-16 .. m0+143
    int pv = (p >= 0) && (p < M_TOTAL);
    int pc = pv ? p : 0;
    int bb = pc / HW, rem = pc - bb * HW;
    int hh = rem / 56;
    abase[j] = aqn + (size_t)q * PLANE + (size_t)pc * 16;
    zbase[j] = zp + q * 16;
    avalid[j] = pv;
    ah[j] = hh;
  }
  // ---- B staging: 24 groups of 16 rows (384 rows = [dwi 3][ocr 128]);
  //      wave w takes groups w*3 .. w*3+2.
  const char* bbase[3];
  #pragma unroll
  for (int i = 0; i < 3; ++i) {
    int slot = (wv * 3 + i) * 16 + (lane >> 2);      // 0..383
    int qp = (((lane & 3) ^ (slot >> 1)) & 3) * 16;
    int dwi_s = slot >> 7, ocr = slot & 127;
    bbase[i] = wqb + ((size_t)(dwi_s * 128 + ocr)) * 256 + qp;
  }
  // ---- w-edge masks per m-fragment
  int lo_ok[4], hi_ok[4];
  #pragma unroll
  for (int mi = 0; mi < 4; ++mi) {
    int m = m0 + wm * 64 + mi * 16 + lr;
    int w = (m % HW) % 56;
    lo_ok[mi] = (w > 0);
    hi_ok[mi] = (w < 55);
  }

  int4v acch[4][2], accl[4][2];
  #pragma unroll
  for (int mi = 0; mi < 4; ++mi)
    #pragma unroll
    for (int ni = 0; ni < 2; ++ni) {
      acch[mi][ni] = (int4v){0, 0, 0, 0};
      accl[mi][ni] = (int4v){0, 0, 0, 0};
    }

  // stage A for step s (s = dh3*4 + icc) into buffer A
  auto stageA = [&](int s, char* A) {
    int dh3 = s >> 2, icc = s & 3;
    int dh = dh3 - 1;
    #pragma unroll
    for (int j = 0; j < 2; ++j) {
      if (j < ng) {
        int h2 = ah[j] + dh;
        bool ok = avalid[j] && ((unsigned)h2 < (unsigned)HH);
        const char* p = ok ? (abase[j] + dh * (56 * 16) + (size_t)icc * (4 * PLANE))
                           : (zbase[j] + icc * 64);
        GLD_LDS16(p, A + sgrp[j] * 1024);
      }
    }
  };
  // stage B for step s into buffer B (3 groups per wave)
  auto stageB = [&](int s, char* B) {
    int dh3 = s >> 2, icc = s & 3;
    #pragma unroll
    for (int i = 0; i < 3; ++i)
      GLD_LDS16(bbase[i] + (size_t)dh3 * 98304 + icc * 64,
                B + ((wv * 3 + i) * 16) * 64);
  };

  // compute step s from buffers A,B
  auto compute = [&](int s, const char* A, const char* B) {
    int icc = s & 3;
    const bool high = (icc < 2);
    const int patv = high ? (int)0x80808080 : 0;  // pad byte per branch
    const int4v pat = (int4v){patv, patv, patv, patv};
    #pragma unroll
    for (int dwi = 0; dwi < 3; ++dwi) {
      int4v af[4], bf[2];
      #pragma unroll
      for (int mi = 0; mi < 4; ++mi) {
        int sA = wm * 64 + mi * 16 + lr + 15 + dwi;
        af[mi] = *(const int4v*)(A + sA * 64 + (((quad ^ (sA >> 1)) & 3) * 16));
        bool ok = (dwi == 1) | (dwi == 0 ? lo_ok[mi] : hi_ok[mi]);
        af[mi] = ok ? af[mi] : pat;
      }
      #pragma unroll
      for (int ni = 0; ni < 2; ++ni) {
        int sB = dwi * 128 + wn * 32 + ni * 16 + lr;
        bf[ni] = *(const int4v*)(B + sB * 64 + (((quad ^ (sB >> 1)) & 3) * 16));
      }
      __builtin_amdgcn_s_setprio(1);
      if (high) {
        #pragma unroll
        for (int mi = 0; mi < 4; ++mi)
          #pragma unroll
          for (int ni = 0; ni < 2; ++ni)
            acch[mi][ni] = __builtin_amdgcn_mfma_i32_16x16x64_i8(
                af[mi], bf[ni], acch[mi][ni], 0, 0, 0);
      } else {
        #pragma unroll
        for (int mi = 0; mi < 4; ++mi)
          #pragma unroll
          for (int ni = 0; ni < 2; ++ni)
            accl[mi][ni] = __builtin_amdgcn_mfma_i32_16x16x64_i8(
                af[mi], bf[ni], accl[mi][ni], 0, 0, 0);
      }
      __builtin_amdgcn_s_setprio(0);
    }
  };

  // ---- pipeline (R9-verified scheme on R14 structure): A 2-deep, B 1-deep.
  // Per-iter: [wait vmcnt(nA)][barrier] stageB(s+1) compute(s) stageA(s+2).
  // At iter-s wait, queue (oldest first) = B(s), A(s+1); vmcnt(nA) forces
  // B(s) + everything older (A(s)) complete, leaves A(s+1) in flight.
  stageA(0, As0);
  stageB(0, Bs0);
  stageA(1, As0 + A_BUF);
  #pragma unroll
  for (int s = 0; s < 12; ++s) {
    if (s == 11) {
      asm volatile("s_waitcnt vmcnt(0)" ::: "memory");
    } else if (wv < 2) {
      asm volatile("s_waitcnt vmcnt(2)" ::: "memory");
    } else {
      asm volatile("s_waitcnt vmcnt(1)" ::: "memory");
    }
    __builtin_amdgcn_s_barrier();        // all waves' step-s data in LDS
    __builtin_amdgcn_sched_barrier(0);   // no LDS-read hoist above barrier
    if (s < 11) stageB(s + 1, Bs0 + ((s + 1) & 1) * B_BUF);
    compute(s, As0 + (s % 3) * A_BUF, Bs0 + (s & 1) * B_BUF);
    if (s < 10) stageA(s + 2, As0 + ((s + 2) % 3) * A_BUF);
  }

  // ---- Epilogue: y = sc_h*acc_h + sc_l*acc_l + bias, plain dwordx4 stores
  #pragma unroll
  for (int mi = 0; mi < 4; ++mi) {
    int m = m0 + wm * 64 + mi * 16 + quad * 4;
    int b = m / HW, r = m - b * HW;
    float* obase = out + (size_t)b * (CH * HW) + r;
    #pragma unroll
    for (int ni = 0; ni < 2; ++ni) {
      int oc = wn * 32 + ni * 16 + lr;
      float sch = scb[oc], scl = scb[128 + oc], bs = scb[256 + oc];
      float4v f;
      #pragma unroll
      for (int rg = 0; rg < 4; ++rg)
        f[rg] = sch * (float)acch[mi][ni][rg] + scl * (float)accl[mi][ni][rg] + bs;
      *(float4v*)(obase + (size_t)oc * HW) = f;
    }
  }
}

extern "C" void kernel_launch(void* const* d_in, const int* in_sizes, int n_in,
                              void* d_out, int out_size, void* d_ws, size_t ws_size,
                              hipStream_t stream) {
  const float* x  = (const float*)d_in[0];
  const float* wh = (const float*)d_in[1];
  const float* wl = (const float*)d_in[2];
  const float* sh = (const float*)d_in[3];
  const float* sl = (const float*)d_in[4];
  float* out = (float*)d_out;

  char* ws = (char*)d_ws;
  char* wqb  = ws + WQB_OFF;
  float* scb = (float*)(ws + SCB_OFF);
  int* zp    = (int*)(ws + ZP_OFF);
  char* aqn  = ws + AQN_OFF;

  // allow >64KB dynamic LDS (one-time, host-side attribute; capture-safe)
  static bool lds_attr_set = false;
  if (!lds_attr_set) {
    hipFuncSetAttribute(reinterpret_cast<const void*>(&conv_mfma_kernel),
                        hipFuncAttributeMaxDynamicSharedMemorySize, LDS_TOTAL);
    lds_attr_set = true;
  }

  prep_kernel<<<dim3(BATCH * 7 * 8 + 256), dim3(256), 0, stream>>>(
      x, wh, wl, sh, sl, wqb, scb, zp, aqn);
  conv_mfma_kernel<<<dim3(M_TOTAL / 128), dim3(512), LDS_TOTAL, stream>>>(
      wqb, aqn, (const char*)zp, scb, out);
}